// Round 3
// baseline (476.527 us; speedup 1.0000x reference)
//
#include <hip/hip_runtime.h>

#define B_ 16384
#define E_ 1024
#define H_ 8
#define D_ 128
#define BK 32

typedef _Float16 f16;
typedef _Float16 f16x8 __attribute__((ext_vector_type(8)));
typedef float f32x4 __attribute__((ext_vector_type(4)));

// async global -> LDS, 16B per lane. LDS dest is wave-uniform base + lane*16.
__device__ __forceinline__ void gload16(const f16* g, f16* l) {
    __builtin_amdgcn_global_load_lds(
        (const __attribute__((address_space(1))) void*)g,
        (__attribute__((address_space(3))) void*)l, 16, 0, 0);
}

// LDS XOR swizzle (within each 16-row x 32-col f16 tile staged by one gload16):
//   LDS chunk p (16B) of row r holds global chunk p ^ ((r>>1)&3).
// Write side: lane l (r=l>>2, p=l&3) sources global chunk (l&3)^((l>>3)&3).
// Read side: global chunk lq of row r lives at LDS chunk lq^((r>>1)&3).
// Verified round 2: SQ_LDS_BANK_CONFLICT 1.68e7 -> 0.

// ---------------- f32 -> f16 conversion ----------------
__global__ __launch_bounds__(256) void cvt2_kernel(const float4* __restrict__ s0,
                                                   const float4* __restrict__ s1,
                                                   ushort4* __restrict__ d0,
                                                   ushort4* __restrict__ d1, int n4) {
    const float4* s = blockIdx.y ? s1 : s0;
    ushort4* d = blockIdx.y ? d1 : d0;
    int i = blockIdx.x * 256 + threadIdx.x;
    if (i >= n4) return;
    float4 v = s[i];
    union { ushort4 u; f16 h[4]; } o;
    o.h[0] = (f16)v.x; o.h[1] = (f16)v.y; o.h[2] = (f16)v.z; o.h[3] = (f16)v.w;
    d[i] = o.u;
}

__global__ __launch_bounds__(256) void cvt4_kernel(
    const float4* __restrict__ s0, const float4* __restrict__ s1,
    const float4* __restrict__ s2, const float4* __restrict__ s3,
    ushort4* __restrict__ d0, ushort4* __restrict__ d1,
    ushort4* __restrict__ d2, ushort4* __restrict__ d3, int n4) {
    const float4* s; ushort4* d;
    switch (blockIdx.y) {
        case 0: s = s0; d = d0; break;
        case 1: s = s1; d = d1; break;
        case 2: s = s2; d = d2; break;
        default: s = s3; d = d3; break;
    }
    int i = blockIdx.x * 256 + threadIdx.x;
    if (i >= n4) return;
    float4 v = s[i];
    union { ushort4 u; f16 h[4]; } o;
    o.h[0] = (f16)v.x; o.h[1] = (f16)v.y; o.h[2] = (f16)v.z; o.h[3] = (f16)v.w;
    d[i] = o.u;
}

// ---------------- fused single-pass QKV + 2-key attention -> ctx ----------------
// grid: (B/64, H). 256 threads = 4 waves, wave grid 2x2 over (64 rows x 128 head cols).
// One K-pass computes Q, Kimg, Ksig, Vimg, Vsig; epilogue mixes ctx = a0*Vi + a1*Vs.
// Double-buffered: stage(t+1) issued before compute(t); one barrier per K-step.
__global__ __launch_bounds__(256, 2) void qkv_attn_kernel(
    const f16* __restrict__ Xi, const f16* __restrict__ Xs,
    const f16* __restrict__ Wq, const f16* __restrict__ Wk, const f16* __restrict__ Wv,
    const float* __restrict__ bq, const float* __restrict__ bk, const float* __restrict__ bv,
    f16* __restrict__ ctx)
{
    __shared__ f16 sAi[2][64][BK];    // 8 KB
    __shared__ f16 sAs[2][64][BK];    // 8 KB
    __shared__ f16 sWq[2][128][BK];   // 16 KB
    __shared__ f16 sWk[2][128][BK];   // 16 KB
    __shared__ f16 sWv[2][128][BK];   // 16 KB   (tiles: 64 KB, 2 blocks/CU)
    __shared__ float sdot[2][64][2];
    __shared__ float sa0[64];

    const int tid  = threadIdx.x;
    const int lane = tid & 63;
    const int wave = tid >> 6;
    const int wr = wave >> 1, wc = wave & 1;
    const int l16 = lane & 15, lq = lane >> 4;

    const int row0 = blockIdx.x * 64;
    const int col0 = blockIdx.y * D_;   // head slice in E

    // per-lane global source addressing for gload16, source column XOR-swizzled
    const int lr = lane >> 2;                                   // 0..15
    const int lc = ((lane & 3) ^ ((lane >> 3) & 3)) * 8;        // swizzled chunk
    const int rc = (lq ^ ((l16 >> 1) & 3)) * 8;                 // swizzled read col

    const f16* gAi = Xi + (size_t)(row0 + wave * 16 + lr) * E_ + lc;
    const f16* gAs = Xs + (size_t)(row0 + wave * 16 + lr) * E_ + lc;
    const size_t woff = (size_t)(col0 + wave * 32 + lr) * E_ + lc;
    const f16* gWq = Wq + woff;
    const f16* gWk = Wk + woff;
    const f16* gWv = Wv + woff;
    const size_t wskip = (size_t)16 * E_;

    f32x4 zero4 = {0.f, 0.f, 0.f, 0.f};
    f32x4 accQ[2][4], accKi[2][4], accKs[2][4], accVi[2][4], accVs[2][4];
    #pragma unroll
    for (int i = 0; i < 2; i++)
        #pragma unroll
        for (int j = 0; j < 4; j++) {
            accQ[i][j] = zero4; accKi[i][j] = zero4; accKs[i][j] = zero4;
            accVi[i][j] = zero4; accVs[i][j] = zero4;
        }

    auto stage = [&](int buf, int kk) {
        gload16(gAi + kk,         &sAi[buf][wave * 16][0]);
        gload16(gAs + kk,         &sAs[buf][wave * 16][0]);
        gload16(gWq + kk,         &sWq[buf][wave * 32][0]);
        gload16(gWq + wskip + kk, &sWq[buf][wave * 32 + 16][0]);
        gload16(gWk + kk,         &sWk[buf][wave * 32][0]);
        gload16(gWk + wskip + kk, &sWk[buf][wave * 32 + 16][0]);
        gload16(gWv + kk,         &sWv[buf][wave * 32][0]);
        gload16(gWv + wskip + kk, &sWv[buf][wave * 32 + 16][0]);
    };

    stage(0, 0);
    __syncthreads();   // buf0 resident

    const int NT = E_ / BK;   // 32
    for (int t = 0; t < NT; ++t) {
        const int cur = t & 1;
        if (t + 1 < NT) stage(cur ^ 1, (t + 1) * BK);   // prefetch rides under compute

        f16x8 aI[2], aS[2], bF[4];
        #pragma unroll
        for (int fr = 0; fr < 2; fr++) {
            aI[fr] = *(const f16x8*)&sAi[cur][wr * 32 + fr * 16 + l16][rc];
            aS[fr] = *(const f16x8*)&sAs[cur][wr * 32 + fr * 16 + l16][rc];
        }
        // Q
        #pragma unroll
        for (int fc = 0; fc < 4; fc++)
            bF[fc] = *(const f16x8*)&sWq[cur][wc * 64 + fc * 16 + l16][rc];
        #pragma unroll
        for (int fr = 0; fr < 2; fr++)
            #pragma unroll
            for (int fc = 0; fc < 4; fc++)
                accQ[fr][fc] = __builtin_amdgcn_mfma_f32_16x16x32_f16(aI[fr], bF[fc], accQ[fr][fc], 0, 0, 0);
        // K (both modalities share B-frag)
        #pragma unroll
        for (int fc = 0; fc < 4; fc++)
            bF[fc] = *(const f16x8*)&sWk[cur][wc * 64 + fc * 16 + l16][rc];
        #pragma unroll
        for (int fr = 0; fr < 2; fr++)
            #pragma unroll
            for (int fc = 0; fc < 4; fc++) {
                accKi[fr][fc] = __builtin_amdgcn_mfma_f32_16x16x32_f16(aI[fr], bF[fc], accKi[fr][fc], 0, 0, 0);
                accKs[fr][fc] = __builtin_amdgcn_mfma_f32_16x16x32_f16(aS[fr], bF[fc], accKs[fr][fc], 0, 0, 0);
            }
        // V (both modalities share B-frag)
        #pragma unroll
        for (int fc = 0; fc < 4; fc++)
            bF[fc] = *(const f16x8*)&sWv[cur][wc * 64 + fc * 16 + l16][rc];
        #pragma unroll
        for (int fr = 0; fr < 2; fr++)
            #pragma unroll
            for (int fc = 0; fc < 4; fc++) {
                accVi[fr][fc] = __builtin_amdgcn_mfma_f32_16x16x32_f16(aI[fr], bF[fc], accVi[fr][fc], 0, 0, 0);
                accVs[fr][fc] = __builtin_amdgcn_mfma_f32_16x16x32_f16(aS[fr], bF[fc], accVs[fr][fc], 0, 0, 0);
            }
        __syncthreads();   // drains prefetch vmcnt + guards cur-buffer reuse
    }

    // biases on score paths (zero in practice but correct in general)
    #pragma unroll
    for (int fc = 0; fc < 4; fc++) {
        int col = col0 + wc * 64 + fc * 16 + l16;
        float bqv = bq[col], bkv = bk[col];
        #pragma unroll
        for (int fr = 0; fr < 2; fr++)
            #pragma unroll
            for (int e = 0; e < 4; e++) {
                accQ[fr][fc][e]  += bqv;
                accKi[fr][fc][e] += bkv;
                accKs[fr][fc][e] += bkv;
            }
    }

    // scores: per-row dot(q,k) over this head's 128 cols
    // C layout: col = lane&15, row = (lane>>4)*4 + e (within 16x16 frag)
    #pragma unroll
    for (int fr = 0; fr < 2; fr++)
        #pragma unroll
        for (int e = 0; e < 4; e++) {
            float d0 = 0.f, d1 = 0.f;
            #pragma unroll
            for (int fc = 0; fc < 4; fc++) {
                d0 += accQ[fr][fc][e] * accKi[fr][fc][e];
                d1 += accQ[fr][fc][e] * accKs[fr][fc][e];
            }
            #pragma unroll
            for (int m = 1; m < 16; m <<= 1) {
                d0 += __shfl_xor(d0, m, 64);
                d1 += __shfl_xor(d1, m, 64);
            }
            if (l16 == 0) {
                int row = wr * 32 + fr * 16 + lq * 4 + e;
                sdot[0][row][wc] = d0;
                sdot[1][row][wc] = d1;
            }
        }
    __syncthreads();
    if (tid < 64) {
        const float scale = 0.088388347648318447f;  // 1/sqrt(128)
        float s0 = (sdot[0][tid][0] + sdot[0][tid][1]) * scale;
        float s1 = (sdot[1][tid][0] + sdot[1][tid][1]) * scale;
        sa0[tid] = 1.0f / (1.0f + expf(s1 - s0));
    }
    __syncthreads();

    // ctx = a0*Vimg + a1*Vsig + bv, written f16
    #pragma unroll
    for (int fc = 0; fc < 4; fc++) {
        int col = col0 + wc * 64 + fc * 16 + l16;
        float bvv = bv[col];
        #pragma unroll
        for (int fr = 0; fr < 2; fr++)
            #pragma unroll
            for (int e = 0; e < 4; e++) {
                int row = wr * 32 + fr * 16 + lq * 4 + e;
                float a0 = sa0[row];
                float v  = a0 * accVi[fr][fc][e] + (1.0f - a0) * accVs[fr][fc][e] + bvv;
                ctx[(size_t)(row0 + row) * E_ + col] = (f16)v;
            }
    }
}

// ---------------- out projection: attn16 = ctx @ Wo^T + bo   (f16, no resid) ------
// grid (B/128, E/128), 256 threads, 4 waves each 64x64 (4x4 frags). dbuf 2-phase.
__global__ __launch_bounds__(256) void out_proj_kernel(
    const f16* __restrict__ A, const f16* __restrict__ Wo, const float* __restrict__ bo,
    f16* __restrict__ a16)
{
    __shared__ f16 sA[2][128][BK];
    __shared__ f16 sB[2][128][BK];
    const int tid  = threadIdx.x;
    const int lane = tid & 63;
    const int wave = tid >> 6;
    const int wr = wave >> 1, wc = wave & 1;
    const int l16 = lane & 15, lq = lane >> 4;
    const int row0 = blockIdx.x * 128;
    const int col0 = blockIdx.y * 128;

    const int lr = lane >> 2;
    const int lc = ((lane & 3) ^ ((lane >> 3) & 3)) * 8;   // swizzled source chunk
    const int rc = (lq ^ ((l16 >> 1) & 3)) * 8;            // swizzled read col

    const f16* gA0 = A  + (size_t)(row0 + wave * 32 + lr) * E_ + lc;
    const f16* gB0 = Wo + (size_t)(col0 + wave * 32 + lr) * E_ + lc;
    const size_t wskip = (size_t)16 * E_;

    f32x4 zero4 = {0.f, 0.f, 0.f, 0.f};
    f32x4 acc[4][4];
    #pragma unroll
    for (int i = 0; i < 4; i++)
        #pragma unroll
        for (int j = 0; j < 4; j++) acc[i][j] = zero4;

    auto stage = [&](int buf, int kk) {
        gload16(gA0 + kk,         &sA[buf][wave * 32][0]);
        gload16(gA0 + wskip + kk, &sA[buf][wave * 32 + 16][0]);
        gload16(gB0 + kk,         &sB[buf][wave * 32][0]);
        gload16(gB0 + wskip + kk, &sB[buf][wave * 32 + 16][0]);
    };

    stage(0, 0);
    __syncthreads();

    const int NT = E_ / BK;   // 32
    for (int t = 0; t < NT; ++t) {
        const int cur = t & 1;
        if (t + 1 < NT) stage(cur ^ 1, (t + 1) * BK);

        f16x8 aF[4], bF[4];
        #pragma unroll
        for (int f = 0; f < 4; f++) {
            aF[f] = *(const f16x8*)&sA[cur][wr * 64 + f * 16 + l16][rc];
            bF[f] = *(const f16x8*)&sB[cur][wc * 64 + f * 16 + l16][rc];
        }
        #pragma unroll
        for (int fr = 0; fr < 4; fr++)
            #pragma unroll
            for (int fc = 0; fc < 4; fc++)
                acc[fr][fc] = __builtin_amdgcn_mfma_f32_16x16x32_f16(aF[fr], bF[fc], acc[fr][fc], 0, 0, 0);
        __syncthreads();
    }

    #pragma unroll
    for (int fc = 0; fc < 4; fc++) {
        int col = col0 + wc * 64 + fc * 16 + l16;
        float bov = bo[col];
        #pragma unroll
        for (int fr = 0; fr < 4; fr++)
            #pragma unroll
            for (int e = 0; e < 4; e++) {
                int row = row0 + wr * 64 + fr * 16 + lq * 4 + e;
                a16[(size_t)row * E_ + col] = (f16)(acc[fr][fc][e] + bov);
            }
    }
}

// ---------------- resid-add + LayerNorm over E=1024 ----------------
// reads attn16 (f16) + image (f32 residual); writes normalized f32
__global__ __launch_bounds__(256) void ln_kernel(
    const f16* __restrict__ a16, const float* __restrict__ resid,
    const float* __restrict__ gamma, const float* __restrict__ beta,
    float* __restrict__ out)
{
    const int row = blockIdx.x;
    const int tid = threadIdx.x;
    union { ushort4 u; f16 h[4]; } ua;
    ua.u = ((const ushort4*)(a16 + (size_t)row * E_))[tid];
    float4 rv = ((const float4*)(resid + (size_t)row * E_))[tid];
    float4 v;
    v.x = (float)ua.h[0] + rv.x;
    v.y = (float)ua.h[1] + rv.y;
    v.z = (float)ua.h[2] + rv.z;
    v.w = (float)ua.h[3] + rv.w;
    float s  = v.x + v.y + v.z + v.w;
    float s2 = v.x * v.x + v.y * v.y + v.z * v.z + v.w * v.w;
    #pragma unroll
    for (int m = 1; m < 64; m <<= 1) {
        s  += __shfl_xor(s, m, 64);
        s2 += __shfl_xor(s2, m, 64);
    }
    __shared__ float red[8];
    int wv = tid >> 6, ln = tid & 63;
    if (ln == 0) { red[wv] = s; red[4 + wv] = s2; }
    __syncthreads();
    s  = red[0] + red[1] + red[2] + red[3];
    s2 = red[4] + red[5] + red[6] + red[7];
    float mu  = s * (1.0f / E_);
    float var = s2 * (1.0f / E_) - mu * mu;
    float r   = rsqrtf(var + 1e-5f);
    float4 g  = ((const float4*)gamma)[tid];
    float4 bb = ((const float4*)beta)[tid];
    float4 o;
    o.x = (v.x - mu) * r * g.x + bb.x;
    o.y = (v.y - mu) * r * g.y + bb.y;
    o.z = (v.z - mu) * r * g.z + bb.z;
    o.w = (v.w - mu) * r * g.w + bb.w;
    ((float4*)(out + (size_t)row * E_))[tid] = o;
}

extern "C" void kernel_launch(void* const* d_in, const int* in_sizes, int n_in,
                              void* d_out, int out_size, void* d_ws, size_t ws_size,
                              hipStream_t stream)
{
    (void)in_sizes; (void)n_in; (void)out_size; (void)ws_size;
    const float* image  = (const float*)d_in[0];
    const float* signal = (const float*)d_in[1];
    const float* Wq = (const float*)d_in[2];
    const float* Wk = (const float*)d_in[3];
    const float* Wv = (const float*)d_in[4];
    const float* bq = (const float*)d_in[5];
    const float* bk = (const float*)d_in[6];
    const float* bv = (const float*)d_in[7];
    const float* Wo = (const float*)d_in[8];
    const float* bo = (const float*)d_in[9];
    const float* gamma = (const float*)d_in[10];
    const float* beta  = (const float*)d_in[11];
    float* out = (float*)d_out;

    char* ws = (char*)d_ws;
    f16* Xi16 = (f16*)(ws);                            // 32 MB (reused as a16 later)
    f16* Xs16 = (f16*)(ws + 32ull * 1024 * 1024);      // 32 MB
    f16* Wq16 = (f16*)(ws + 64ull * 1024 * 1024);      // 2 MB
    f16* Wk16 = (f16*)(ws + 66ull * 1024 * 1024);      // 2 MB
    f16* Wv16 = (f16*)(ws + 68ull * 1024 * 1024);      // 2 MB
    f16* Wo16 = (f16*)(ws + 70ull * 1024 * 1024);      // 2 MB
    f16* ctx  = (f16*)(ws + 72ull * 1024 * 1024);      // 32 MB  (total 104 MB)
    f16* a16  = Xi16;                                  // Xi16 dead after qkv

    const int nBE4 = B_ * E_ / 4;   // 4194304
    const int nEE4 = E_ * E_ / 4;   // 262144
    dim3 gX(nBE4 / 256, 2);
    cvt2_kernel<<<gX, 256, 0, stream>>>((const float4*)image, (const float4*)signal,
                                        (ushort4*)Xi16, (ushort4*)Xs16, nBE4);
    dim3 gW(nEE4 / 256, 4);
    cvt4_kernel<<<gW, 256, 0, stream>>>((const float4*)Wq, (const float4*)Wk,
                                        (const float4*)Wv, (const float4*)Wo,
                                        (ushort4*)Wq16, (ushort4*)Wk16,
                                        (ushort4*)Wv16, (ushort4*)Wo16, nEE4);

    dim3 g2(B_ / 64, H_);
    qkv_attn_kernel<<<g2, 256, 0, stream>>>(Xi16, Xs16, Wq16, Wk16, Wv16, bq, bk, bv, ctx);

    dim3 g4(B_ / 128, E_ / 128);
    out_proj_kernel<<<g4, 256, 0, stream>>>(ctx, Wo16, bo, a16);

    ln_kernel<<<B_, 256, 0, stream>>>(a16, image, gamma, beta, out);
}

// Round 4
// 444.317 us; speedup vs baseline: 1.0725x; 1.0725x over previous
//
#include <hip/hip_runtime.h>

#define B_ 16384
#define E_ 1024
#define H_ 8
#define D_ 128

typedef _Float16 f16;
typedef _Float16 f16x8 __attribute__((ext_vector_type(8)));
typedef float f32x4 __attribute__((ext_vector_type(4)));

// async global -> LDS, 16B per lane. LDS dest is wave-uniform base + lane*16.
__device__ __forceinline__ void gload16(const f16* g, f16* l) {
    __builtin_amdgcn_global_load_lds(
        (const __attribute__((address_space(1))) void*)g,
        (__attribute__((address_space(3))) void*)l, 16, 0, 0);
}

// LDS XOR swizzle (within each 16-row x 32-col f16 tile staged by one gload16):
//   LDS chunk p (16B) of row r holds global chunk p ^ ((r>>1)&3).
// Write side: lane l (r=l>>2, p=l&3) sources global chunk (l&3)^((l>>3)&3).
// Read side: global chunk lq of row r lives at LDS chunk lq^((r>>1)&3).
// Verified round 2: SQ_LDS_BANK_CONFLICT 1.68e7 -> 0.
// BK=64 keeps this by storing the two 32-col halves as separate [2][rows][32]
// arrays (row stride stays 64 B; per-half pattern identical).

// ---------------- f32 -> f16 conversion ----------------
__global__ __launch_bounds__(256) void cvt2_kernel(const float4* __restrict__ s0,
                                                   const float4* __restrict__ s1,
                                                   ushort4* __restrict__ d0,
                                                   ushort4* __restrict__ d1, int n4) {
    const float4* s = blockIdx.y ? s1 : s0;
    ushort4* d = blockIdx.y ? d1 : d0;
    int i = blockIdx.x * 256 + threadIdx.x;
    if (i >= n4) return;
    float4 v = s[i];
    union { ushort4 u; f16 h[4]; } o;
    o.h[0] = (f16)v.x; o.h[1] = (f16)v.y; o.h[2] = (f16)v.z; o.h[3] = (f16)v.w;
    d[i] = o.u;
}

__global__ __launch_bounds__(256) void cvt4_kernel(
    const float4* __restrict__ s0, const float4* __restrict__ s1,
    const float4* __restrict__ s2, const float4* __restrict__ s3,
    ushort4* __restrict__ d0, ushort4* __restrict__ d1,
    ushort4* __restrict__ d2, ushort4* __restrict__ d3, int n4) {
    const float4* s; ushort4* d;
    switch (blockIdx.y) {
        case 0: s = s0; d = d0; break;
        case 1: s = s1; d = d1; break;
        case 2: s = s2; d = d2; break;
        default: s = s3; d = d3; break;
    }
    int i = blockIdx.x * 256 + threadIdx.x;
    if (i >= n4) return;
    float4 v = s[i];
    union { ushort4 u; f16 h[4]; } o;
    o.h[0] = (f16)v.x; o.h[1] = (f16)v.y; o.h[2] = (f16)v.z; o.h[3] = (f16)v.w;
    d[i] = o.u;
}

// ---------------- fused single-pass QKV + 2-key attention -> ctx ----------------
// 1-D grid of 2048 blocks; head = bid & 7 (one head per XCD for W L2-locality),
// rblk = bid >> 3. 256 threads = 4 waves, wave grid 2x2 over 64 rows x 128 cols.
// One K-pass computes Q, Kimg, Ksig, Vimg, Vsig; epilogue mixes ctx = a0*Vi+a1*Vs.
// Single-buffered (1-phase proven faster than dbuf here, rounds 2 vs 3), BK=64:
// half the barrier-drain events of BK=32.
__global__ __launch_bounds__(256, 2) void qkv_attn_kernel(
    const f16* __restrict__ Xi, const f16* __restrict__ Xs,
    const f16* __restrict__ Wq, const f16* __restrict__ Wk, const f16* __restrict__ Wv,
    const float* __restrict__ bq, const float* __restrict__ bk, const float* __restrict__ bv,
    f16* __restrict__ ctx)
{
    __shared__ f16 sAi[2][64][32];    // [half][row][col]  8 KB
    __shared__ f16 sAs[2][64][32];    //                   8 KB
    __shared__ f16 sWq[2][128][32];   //                  16 KB
    __shared__ f16 sWk[2][128][32];   //                  16 KB
    __shared__ f16 sWv[2][128][32];   //                  16 KB  (64 KB -> 2 blocks/CU)
    __shared__ float sdot[2][64][2];
    __shared__ float sa0[64];

    const int tid  = threadIdx.x;
    const int lane = tid & 63;
    const int wave = tid >> 6;
    const int wr = wave >> 1, wc = wave & 1;
    const int l16 = lane & 15, lq = lane >> 4;

    const int bid  = blockIdx.x;
    const int head = bid & 7;           // XCD-aligned head assignment
    const int row0 = (bid >> 3) * 64;
    const int col0 = head * D_;

    // per-lane global source addressing for gload16, source column XOR-swizzled
    const int lr = lane >> 2;                                   // 0..15
    const int lc = ((lane & 3) ^ ((lane >> 3) & 3)) * 8;        // swizzled chunk
    const int rc = (lq ^ ((l16 >> 1) & 3)) * 8;                 // swizzled read col

    const f16* gAi = Xi + (size_t)(row0 + wave * 16 + lr) * E_ + lc;
    const f16* gAs = Xs + (size_t)(row0 + wave * 16 + lr) * E_ + lc;
    const size_t woff = (size_t)(col0 + wave * 32 + lr) * E_ + lc;
    const f16* gWq = Wq + woff;
    const f16* gWk = Wk + woff;
    const f16* gWv = Wv + woff;
    const size_t wskip = (size_t)16 * E_;

    f32x4 zero4 = {0.f, 0.f, 0.f, 0.f};
    f32x4 accQ[2][4], accKi[2][4], accKs[2][4], accVi[2][4], accVs[2][4];
    #pragma unroll
    for (int i = 0; i < 2; i++)
        #pragma unroll
        for (int j = 0; j < 4; j++) {
            accQ[i][j] = zero4; accKi[i][j] = zero4; accKs[i][j] = zero4;
            accVi[i][j] = zero4; accVs[i][j] = zero4;
        }

    for (int kk = 0; kk < E_; kk += 64) {
        // stage both 32-col halves of the K64 tile (16 gload16 per wave)
        #pragma unroll
        for (int h = 0; h < 2; h++) {
            const int ko = kk + h * 32;
            gload16(gAi + ko,         &sAi[h][wave * 16][0]);
            gload16(gAs + ko,         &sAs[h][wave * 16][0]);
            gload16(gWq + ko,         &sWq[h][wave * 32][0]);
            gload16(gWq + wskip + ko, &sWq[h][wave * 32 + 16][0]);
            gload16(gWk + ko,         &sWk[h][wave * 32][0]);
            gload16(gWk + wskip + ko, &sWk[h][wave * 32 + 16][0]);
            gload16(gWv + ko,         &sWv[h][wave * 32][0]);
            gload16(gWv + wskip + ko, &sWv[h][wave * 32 + 16][0]);
        }
        __syncthreads();   // drains vmcnt -> tile resident

        #pragma unroll
        for (int h = 0; h < 2; h++) {
            f16x8 aI[2], aS[2], bF[4];
            #pragma unroll
            for (int fr = 0; fr < 2; fr++) {
                aI[fr] = *(const f16x8*)&sAi[h][wr * 32 + fr * 16 + l16][rc];
                aS[fr] = *(const f16x8*)&sAs[h][wr * 32 + fr * 16 + l16][rc];
            }
            // Q
            #pragma unroll
            for (int fc = 0; fc < 4; fc++)
                bF[fc] = *(const f16x8*)&sWq[h][wc * 64 + fc * 16 + l16][rc];
            #pragma unroll
            for (int fr = 0; fr < 2; fr++)
                #pragma unroll
                for (int fc = 0; fc < 4; fc++)
                    accQ[fr][fc] = __builtin_amdgcn_mfma_f32_16x16x32_f16(aI[fr], bF[fc], accQ[fr][fc], 0, 0, 0);
            // K (both modalities share B-frag)
            #pragma unroll
            for (int fc = 0; fc < 4; fc++)
                bF[fc] = *(const f16x8*)&sWk[h][wc * 64 + fc * 16 + l16][rc];
            #pragma unroll
            for (int fr = 0; fr < 2; fr++)
                #pragma unroll
                for (int fc = 0; fc < 4; fc++) {
                    accKi[fr][fc] = __builtin_amdgcn_mfma_f32_16x16x32_f16(aI[fr], bF[fc], accKi[fr][fc], 0, 0, 0);
                    accKs[fr][fc] = __builtin_amdgcn_mfma_f32_16x16x32_f16(aS[fr], bF[fc], accKs[fr][fc], 0, 0, 0);
                }
            // V (both modalities share B-frag)
            #pragma unroll
            for (int fc = 0; fc < 4; fc++)
                bF[fc] = *(const f16x8*)&sWv[h][wc * 64 + fc * 16 + l16][rc];
            #pragma unroll
            for (int fr = 0; fr < 2; fr++)
                #pragma unroll
                for (int fc = 0; fc < 4; fc++) {
                    accVi[fr][fc] = __builtin_amdgcn_mfma_f32_16x16x32_f16(aI[fr], bF[fc], accVi[fr][fc], 0, 0, 0);
                    accVs[fr][fc] = __builtin_amdgcn_mfma_f32_16x16x32_f16(aS[fr], bF[fc], accVs[fr][fc], 0, 0, 0);
                }
        }
        __syncthreads();   // guard LDS reuse next iteration
    }

    // biases on score paths (zero in practice but correct in general)
    #pragma unroll
    for (int fc = 0; fc < 4; fc++) {
        int col = col0 + wc * 64 + fc * 16 + l16;
        float bqv = bq[col], bkv = bk[col];
        #pragma unroll
        for (int fr = 0; fr < 2; fr++)
            #pragma unroll
            for (int e = 0; e < 4; e++) {
                accQ[fr][fc][e]  += bqv;
                accKi[fr][fc][e] += bkv;
                accKs[fr][fc][e] += bkv;
            }
    }

    // scores: per-row dot(q,k) over this head's 128 cols
    // C layout: col = lane&15, row = (lane>>4)*4 + e (within 16x16 frag)
    #pragma unroll
    for (int fr = 0; fr < 2; fr++)
        #pragma unroll
        for (int e = 0; e < 4; e++) {
            float d0 = 0.f, d1 = 0.f;
            #pragma unroll
            for (int fc = 0; fc < 4; fc++) {
                d0 += accQ[fr][fc][e] * accKi[fr][fc][e];
                d1 += accQ[fr][fc][e] * accKs[fr][fc][e];
            }
            #pragma unroll
            for (int m = 1; m < 16; m <<= 1) {
                d0 += __shfl_xor(d0, m, 64);
                d1 += __shfl_xor(d1, m, 64);
            }
            if (l16 == 0) {
                int row = wr * 32 + fr * 16 + lq * 4 + e;
                sdot[0][row][wc] = d0;
                sdot[1][row][wc] = d1;
            }
        }
    __syncthreads();
    if (tid < 64) {
        const float scale = 0.088388347648318447f;  // 1/sqrt(128)
        float s0 = (sdot[0][tid][0] + sdot[0][tid][1]) * scale;
        float s1 = (sdot[1][tid][0] + sdot[1][tid][1]) * scale;
        sa0[tid] = 1.0f / (1.0f + expf(s1 - s0));
    }
    __syncthreads();

    // ctx = a0*Vimg + a1*Vsig + bv, written f16
    #pragma unroll
    for (int fc = 0; fc < 4; fc++) {
        int col = col0 + wc * 64 + fc * 16 + l16;
        float bvv = bv[col];
        #pragma unroll
        for (int fr = 0; fr < 2; fr++)
            #pragma unroll
            for (int e = 0; e < 4; e++) {
                int row = wr * 32 + fr * 16 + lq * 4 + e;
                float a0 = sa0[row];
                float v  = a0 * accVi[fr][fc][e] + (1.0f - a0) * accVs[fr][fc][e] + bvv;
                ctx[(size_t)(row0 + row) * E_ + col] = (f16)v;
            }
    }
}

// ---------------- out projection: attn16 = ctx @ Wo^T + bo   (f16, no resid) ------
// grid (B/128, E/128), 256 threads, 4 waves each 64x64 (4x4 frags).
// Single-buffer BK=64, 1-phase (same template as qkv).
__global__ __launch_bounds__(256) void out_proj_kernel(
    const f16* __restrict__ A, const f16* __restrict__ Wo, const float* __restrict__ bo,
    f16* __restrict__ a16)
{
    __shared__ f16 sA[2][128][32];   // [half][row][col] 16 KB
    __shared__ f16 sB[2][128][32];   //                  16 KB
    const int tid  = threadIdx.x;
    const int lane = tid & 63;
    const int wave = tid >> 6;
    const int wr = wave >> 1, wc = wave & 1;
    const int l16 = lane & 15, lq = lane >> 4;
    const int row0 = blockIdx.x * 128;
    const int col0 = blockIdx.y * 128;

    const int lr = lane >> 2;
    const int lc = ((lane & 3) ^ ((lane >> 3) & 3)) * 8;   // swizzled source chunk
    const int rc = (lq ^ ((l16 >> 1) & 3)) * 8;            // swizzled read col

    const f16* gA0 = A  + (size_t)(row0 + wave * 32 + lr) * E_ + lc;
    const f16* gB0 = Wo + (size_t)(col0 + wave * 32 + lr) * E_ + lc;
    const size_t wskip = (size_t)16 * E_;

    f32x4 zero4 = {0.f, 0.f, 0.f, 0.f};
    f32x4 acc[4][4];
    #pragma unroll
    for (int i = 0; i < 4; i++)
        #pragma unroll
        for (int j = 0; j < 4; j++) acc[i][j] = zero4;

    for (int kk = 0; kk < E_; kk += 64) {
        #pragma unroll
        for (int h = 0; h < 2; h++) {
            const int ko = kk + h * 32;
            gload16(gA0 + ko,         &sA[h][wave * 32][0]);
            gload16(gA0 + wskip + ko, &sA[h][wave * 32 + 16][0]);
            gload16(gB0 + ko,         &sB[h][wave * 32][0]);
            gload16(gB0 + wskip + ko, &sB[h][wave * 32 + 16][0]);
        }
        __syncthreads();

        #pragma unroll
        for (int h = 0; h < 2; h++) {
            f16x8 aF[4], bF[4];
            #pragma unroll
            for (int f = 0; f < 4; f++) {
                aF[f] = *(const f16x8*)&sA[h][wr * 64 + f * 16 + l16][rc];
                bF[f] = *(const f16x8*)&sB[h][wc * 64 + f * 16 + l16][rc];
            }
            #pragma unroll
            for (int fr = 0; fr < 4; fr++)
                #pragma unroll
                for (int fc = 0; fc < 4; fc++)
                    acc[fr][fc] = __builtin_amdgcn_mfma_f32_16x16x32_f16(aF[fr], bF[fc], acc[fr][fc], 0, 0, 0);
        }
        __syncthreads();
    }

    #pragma unroll
    for (int fc = 0; fc < 4; fc++) {
        int col = col0 + wc * 64 + fc * 16 + l16;
        float bov = bo[col];
        #pragma unroll
        for (int fr = 0; fr < 4; fr++)
            #pragma unroll
            for (int e = 0; e < 4; e++) {
                int row = row0 + wr * 64 + fr * 16 + lq * 4 + e;
                a16[(size_t)row * E_ + col] = (f16)(acc[fr][fc][e] + bov);
            }
    }
}

// ---------------- resid-add + LayerNorm over E=1024 ----------------
// reads attn16 (f16) + image (f32 residual); writes normalized f32
__global__ __launch_bounds__(256) void ln_kernel(
    const f16* __restrict__ a16, const float* __restrict__ resid,
    const float* __restrict__ gamma, const float* __restrict__ beta,
    float* __restrict__ out)
{
    const int row = blockIdx.x;
    const int tid = threadIdx.x;
    union { ushort4 u; f16 h[4]; } ua;
    ua.u = ((const ushort4*)(a16 + (size_t)row * E_))[tid];
    float4 rv = ((const float4*)(resid + (size_t)row * E_))[tid];
    float4 v;
    v.x = (float)ua.h[0] + rv.x;
    v.y = (float)ua.h[1] + rv.y;
    v.z = (float)ua.h[2] + rv.z;
    v.w = (float)ua.h[3] + rv.w;
    float s  = v.x + v.y + v.z + v.w;
    float s2 = v.x * v.x + v.y * v.y + v.z * v.z + v.w * v.w;
    #pragma unroll
    for (int m = 1; m < 64; m <<= 1) {
        s  += __shfl_xor(s, m, 64);
        s2 += __shfl_xor(s2, m, 64);
    }
    __shared__ float red[8];
    int wv = tid >> 6, ln = tid & 63;
    if (ln == 0) { red[wv] = s; red[4 + wv] = s2; }
    __syncthreads();
    s  = red[0] + red[1] + red[2] + red[3];
    s2 = red[4] + red[5] + red[6] + red[7];
    float mu  = s * (1.0f / E_);
    float var = s2 * (1.0f / E_) - mu * mu;
    float r   = rsqrtf(var + 1e-5f);
    float4 g  = ((const float4*)gamma)[tid];
    float4 bb = ((const float4*)beta)[tid];
    float4 o;
    o.x = (v.x - mu) * r * g.x + bb.x;
    o.y = (v.y - mu) * r * g.y + bb.y;
    o.z = (v.z - mu) * r * g.z + bb.z;
    o.w = (v.w - mu) * r * g.w + bb.w;
    ((float4*)(out + (size_t)row * E_))[tid] = o;
}

extern "C" void kernel_launch(void* const* d_in, const int* in_sizes, int n_in,
                              void* d_out, int out_size, void* d_ws, size_t ws_size,
                              hipStream_t stream)
{
    (void)in_sizes; (void)n_in; (void)out_size; (void)ws_size;
    const float* image  = (const float*)d_in[0];
    const float* signal = (const float*)d_in[1];
    const float* Wq = (const float*)d_in[2];
    const float* Wk = (const float*)d_in[3];
    const float* Wv = (const float*)d_in[4];
    const float* bq = (const float*)d_in[5];
    const float* bk = (const float*)d_in[6];
    const float* bv = (const float*)d_in[7];
    const float* Wo = (const float*)d_in[8];
    const float* bo = (const float*)d_in[9];
    const float* gamma = (const float*)d_in[10];
    const float* beta  = (const float*)d_in[11];
    float* out = (float*)d_out;

    char* ws = (char*)d_ws;
    f16* Xi16 = (f16*)(ws);                            // 32 MB (reused as a16 later)
    f16* Xs16 = (f16*)(ws + 32ull * 1024 * 1024);      // 32 MB
    f16* Wq16 = (f16*)(ws + 64ull * 1024 * 1024);      // 2 MB
    f16* Wk16 = (f16*)(ws + 66ull * 1024 * 1024);      // 2 MB
    f16* Wv16 = (f16*)(ws + 68ull * 1024 * 1024);      // 2 MB
    f16* Wo16 = (f16*)(ws + 70ull * 1024 * 1024);      // 2 MB
    f16* ctx  = (f16*)(ws + 72ull * 1024 * 1024);      // 32 MB  (total 104 MB)
    f16* a16  = Xi16;                                  // Xi16 dead after qkv

    const int nBE4 = B_ * E_ / 4;   // 4194304
    const int nEE4 = E_ * E_ / 4;   // 262144
    dim3 gX(nBE4 / 256, 2);
    cvt2_kernel<<<gX, 256, 0, stream>>>((const float4*)image, (const float4*)signal,
                                        (ushort4*)Xi16, (ushort4*)Xs16, nBE4);
    dim3 gW(nEE4 / 256, 4);
    cvt4_kernel<<<gW, 256, 0, stream>>>((const float4*)Wq, (const float4*)Wk,
                                        (const float4*)Wv, (const float4*)Wo,
                                        (ushort4*)Wq16, (ushort4*)Wk16,
                                        (ushort4*)Wv16, (ushort4*)Wo16, nEE4);

    qkv_attn_kernel<<<B_ / 64 * H_, 256, 0, stream>>>(Xi16, Xs16, Wq16, Wk16, Wv16,
                                                      bq, bk, bv, ctx);

    dim3 g4(B_ / 128, E_ / 128);
    out_proj_kernel<<<g4, 256, 0, stream>>>(ctx, Wo16, bo, a16);

    ln_kernel<<<B_, 256, 0, stream>>>(a16, image, gamma, beta, out);
}

// Round 5
// 440.002 us; speedup vs baseline: 1.0830x; 1.0098x over previous
//
#include <hip/hip_runtime.h>

#define B_ 16384
#define E_ 1024
#define H_ 8
#define D_ 128

typedef _Float16 f16;
typedef _Float16 f16x8 __attribute__((ext_vector_type(8)));
typedef float f32x4 __attribute__((ext_vector_type(4)));

// async global -> LDS, 16B per lane. LDS dest is wave-uniform base + lane*16.
__device__ __forceinline__ void gload16(const f16* g, f16* l) {
    __builtin_amdgcn_global_load_lds(
        (const __attribute__((address_space(1))) void*)g,
        (__attribute__((address_space(3))) void*)l, 16, 0, 0);
}

// LDS XOR swizzle (within each 16-row x 32-col f16 tile staged by one gload16):
//   LDS chunk p (16B) of row r holds global chunk p ^ ((r>>1)&3).
// Write side: lane l (r=l>>2, p=l&3) sources global chunk (l&3)^((l>>3)&3).
// Read side: global chunk lq of row r lives at LDS chunk lq^((r>>1)&3).
// Verified round 2: SQ_LDS_BANK_CONFLICT 1.68e7 -> 0.
// Empirical template law (rounds 2-4): 1-phase single-buffer BK=64 beats dbuf here;
// the lever is MFMA-per-barrier-drain, not pipelining depth.

// ---------------- f32 -> f16 conversion ----------------
__global__ __launch_bounds__(256) void cvt2_kernel(const float4* __restrict__ s0,
                                                   const float4* __restrict__ s1,
                                                   ushort4* __restrict__ d0,
                                                   ushort4* __restrict__ d1, int n4) {
    const float4* s = blockIdx.y ? s1 : s0;
    ushort4* d = blockIdx.y ? d1 : d0;
    int i = blockIdx.x * 256 + threadIdx.x;
    if (i >= n4) return;
    float4 v = s[i];
    union { ushort4 u; f16 h[4]; } o;
    o.h[0] = (f16)v.x; o.h[1] = (f16)v.y; o.h[2] = (f16)v.z; o.h[3] = (f16)v.w;
    d[i] = o.u;
}

__global__ __launch_bounds__(256) void cvt4_kernel(
    const float4* __restrict__ s0, const float4* __restrict__ s1,
    const float4* __restrict__ s2, const float4* __restrict__ s3,
    ushort4* __restrict__ d0, ushort4* __restrict__ d1,
    ushort4* __restrict__ d2, ushort4* __restrict__ d3, int n4) {
    const float4* s; ushort4* d;
    switch (blockIdx.y) {
        case 0: s = s0; d = d0; break;
        case 1: s = s1; d = d1; break;
        case 2: s = s2; d = d2; break;
        default: s = s3; d = d3; break;
    }
    int i = blockIdx.x * 256 + threadIdx.x;
    if (i >= n4) return;
    float4 v = s[i];
    union { ushort4 u; f16 h[4]; } o;
    o.h[0] = (f16)v.x; o.h[1] = (f16)v.y; o.h[2] = (f16)v.z; o.h[3] = (f16)v.w;
    d[i] = o.u;
}

// ---------------- fused single-pass QKV + 2-key attention -> ctx ----------------
// 1-D grid of 2048 blocks; head = bid & 7, rblk = bid >> 3.
// 256 threads = 4 waves, wave grid 2x2 over 64 rows x 128 cols. One K-pass computes
// Q, Kimg, Ksig, Vimg, Vsig; epilogue mixes ctx = a0*Vi + a1*Vs (softmax linearity).
// Single-buffer BK=64 (measured best: r2 195us BK32, r3 234us dbuf, r4 191us BK64).
__global__ __launch_bounds__(256, 2) void qkv_attn_kernel(
    const f16* __restrict__ Xi, const f16* __restrict__ Xs,
    const f16* __restrict__ Wq, const f16* __restrict__ Wk, const f16* __restrict__ Wv,
    const float* __restrict__ bq, const float* __restrict__ bk, const float* __restrict__ bv,
    f16* __restrict__ ctx)
{
    __shared__ f16 sAi[2][64][32];    // [half][row][col]  8 KB
    __shared__ f16 sAs[2][64][32];    //                   8 KB
    __shared__ f16 sWq[2][128][32];   //                  16 KB
    __shared__ f16 sWk[2][128][32];   //                  16 KB
    __shared__ f16 sWv[2][128][32];   //                  16 KB  (64 KB -> 2 blocks/CU)
    __shared__ float sdot[2][64][2];
    __shared__ float sa0[64];

    const int tid  = threadIdx.x;
    const int lane = tid & 63;
    const int wave = tid >> 6;
    const int wr = wave >> 1, wc = wave & 1;
    const int l16 = lane & 15, lq = lane >> 4;

    const int bid  = blockIdx.x;
    const int head = bid & 7;           // XCD-aligned head assignment
    const int row0 = (bid >> 3) * 64;
    const int col0 = head * D_;

    const int lr = lane >> 2;                                   // 0..15
    const int lc = ((lane & 3) ^ ((lane >> 3) & 3)) * 8;        // swizzled src chunk
    const int rc = (lq ^ ((l16 >> 1) & 3)) * 8;                 // swizzled read col

    const f16* gAi = Xi + (size_t)(row0 + wave * 16 + lr) * E_ + lc;
    const f16* gAs = Xs + (size_t)(row0 + wave * 16 + lr) * E_ + lc;
    const size_t woff = (size_t)(col0 + wave * 32 + lr) * E_ + lc;
    const f16* gWq = Wq + woff;
    const f16* gWk = Wk + woff;
    const f16* gWv = Wv + woff;
    const size_t wskip = (size_t)16 * E_;

    f32x4 zero4 = {0.f, 0.f, 0.f, 0.f};
    f32x4 accQ[2][4], accKi[2][4], accKs[2][4], accVi[2][4], accVs[2][4];
    #pragma unroll
    for (int i = 0; i < 2; i++)
        #pragma unroll
        for (int j = 0; j < 4; j++) {
            accQ[i][j] = zero4; accKi[i][j] = zero4; accKs[i][j] = zero4;
            accVi[i][j] = zero4; accVs[i][j] = zero4;
        }

    for (int kk = 0; kk < E_; kk += 64) {
        #pragma unroll
        for (int h = 0; h < 2; h++) {
            const int ko = kk + h * 32;
            gload16(gAi + ko,         &sAi[h][wave * 16][0]);
            gload16(gAs + ko,         &sAs[h][wave * 16][0]);
            gload16(gWq + ko,         &sWq[h][wave * 32][0]);
            gload16(gWq + wskip + ko, &sWq[h][wave * 32 + 16][0]);
            gload16(gWk + ko,         &sWk[h][wave * 32][0]);
            gload16(gWk + wskip + ko, &sWk[h][wave * 32 + 16][0]);
            gload16(gWv + ko,         &sWv[h][wave * 32][0]);
            gload16(gWv + wskip + ko, &sWv[h][wave * 32 + 16][0]);
        }
        __syncthreads();   // drains vmcnt -> tile resident

        #pragma unroll
        for (int h = 0; h < 2; h++) {
            f16x8 aI[2], aS[2], bF[4];
            #pragma unroll
            for (int fr = 0; fr < 2; fr++) {
                aI[fr] = *(const f16x8*)&sAi[h][wr * 32 + fr * 16 + l16][rc];
                aS[fr] = *(const f16x8*)&sAs[h][wr * 32 + fr * 16 + l16][rc];
            }
            #pragma unroll
            for (int fc = 0; fc < 4; fc++)
                bF[fc] = *(const f16x8*)&sWq[h][wc * 64 + fc * 16 + l16][rc];
            #pragma unroll
            for (int fr = 0; fr < 2; fr++)
                #pragma unroll
                for (int fc = 0; fc < 4; fc++)
                    accQ[fr][fc] = __builtin_amdgcn_mfma_f32_16x16x32_f16(aI[fr], bF[fc], accQ[fr][fc], 0, 0, 0);
            #pragma unroll
            for (int fc = 0; fc < 4; fc++)
                bF[fc] = *(const f16x8*)&sWk[h][wc * 64 + fc * 16 + l16][rc];
            #pragma unroll
            for (int fr = 0; fr < 2; fr++)
                #pragma unroll
                for (int fc = 0; fc < 4; fc++) {
                    accKi[fr][fc] = __builtin_amdgcn_mfma_f32_16x16x32_f16(aI[fr], bF[fc], accKi[fr][fc], 0, 0, 0);
                    accKs[fr][fc] = __builtin_amdgcn_mfma_f32_16x16x32_f16(aS[fr], bF[fc], accKs[fr][fc], 0, 0, 0);
                }
            #pragma unroll
            for (int fc = 0; fc < 4; fc++)
                bF[fc] = *(const f16x8*)&sWv[h][wc * 64 + fc * 16 + l16][rc];
            #pragma unroll
            for (int fr = 0; fr < 2; fr++)
                #pragma unroll
                for (int fc = 0; fc < 4; fc++) {
                    accVi[fr][fc] = __builtin_amdgcn_mfma_f32_16x16x32_f16(aI[fr], bF[fc], accVi[fr][fc], 0, 0, 0);
                    accVs[fr][fc] = __builtin_amdgcn_mfma_f32_16x16x32_f16(aS[fr], bF[fc], accVs[fr][fc], 0, 0, 0);
                }
        }
        __syncthreads();   // guard LDS reuse next iteration
    }

    #pragma unroll
    for (int fc = 0; fc < 4; fc++) {
        int col = col0 + wc * 64 + fc * 16 + l16;
        float bqv = bq[col], bkv = bk[col];
        #pragma unroll
        for (int fr = 0; fr < 2; fr++)
            #pragma unroll
            for (int e = 0; e < 4; e++) {
                accQ[fr][fc][e]  += bqv;
                accKi[fr][fc][e] += bkv;
                accKs[fr][fc][e] += bkv;
            }
    }

    // scores: per-row dot(q,k) over this head's 128 cols
    #pragma unroll
    for (int fr = 0; fr < 2; fr++)
        #pragma unroll
        for (int e = 0; e < 4; e++) {
            float d0 = 0.f, d1 = 0.f;
            #pragma unroll
            for (int fc = 0; fc < 4; fc++) {
                d0 += accQ[fr][fc][e] * accKi[fr][fc][e];
                d1 += accQ[fr][fc][e] * accKs[fr][fc][e];
            }
            #pragma unroll
            for (int m = 1; m < 16; m <<= 1) {
                d0 += __shfl_xor(d0, m, 64);
                d1 += __shfl_xor(d1, m, 64);
            }
            if (l16 == 0) {
                int row = wr * 32 + fr * 16 + lq * 4 + e;
                sdot[0][row][wc] = d0;
                sdot[1][row][wc] = d1;
            }
        }
    __syncthreads();
    if (tid < 64) {
        const float scale = 0.088388347648318447f;  // 1/sqrt(128)
        float s0 = (sdot[0][tid][0] + sdot[0][tid][1]) * scale;
        float s1 = (sdot[1][tid][0] + sdot[1][tid][1]) * scale;
        sa0[tid] = 1.0f / (1.0f + expf(s1 - s0));
    }
    __syncthreads();

    // ctx = a0*Vimg + a1*Vsig + bv, written f16
    #pragma unroll
    for (int fc = 0; fc < 4; fc++) {
        int col = col0 + wc * 64 + fc * 16 + l16;
        float bvv = bv[col];
        #pragma unroll
        for (int fr = 0; fr < 2; fr++)
            #pragma unroll
            for (int e = 0; e < 4; e++) {
                int row = wr * 32 + fr * 16 + lq * 4 + e;
                float a0 = sa0[row];
                float v  = a0 * accVi[fr][fc][e] + (1.0f - a0) * accVs[fr][fc][e] + bvv;
                ctx[(size_t)(row0 + row) * E_ + col] = (f16)v;
            }
    }
}

// ---------------- out projection: attn16 = ctx @ Wo^T + bo   (f16) ----------------
// 256x128 tile, 1-D grid of 512 blocks: col-panel = bid&7 (per-XCD Wo L2 residence),
// row-panel = bid>>3. 4 waves; each wave 64 rows x 128 cols = acc[4][8] (64 MFMA per
// wave-iteration -> 2x compute per barrier-drain vs the old 128x128 tile, which sat
// invariant at ~170us/9% util across 4 structural variants).
__global__ __launch_bounds__(256, 2) void out_proj_kernel(
    const f16* __restrict__ A, const f16* __restrict__ Wo, const float* __restrict__ bo,
    f16* __restrict__ a16)
{
    __shared__ f16 sA[2][256][32];   // [half][row][col] 32 KB
    __shared__ f16 sB[2][128][32];   //                  16 KB  (48 KB total)
    const int tid  = threadIdx.x;
    const int lane = tid & 63;
    const int wave = tid >> 6;
    const int l16 = lane & 15, lq = lane >> 4;

    const int bid  = blockIdx.x;
    const int col0 = (bid & 7) * 128;
    const int row0 = (bid >> 3) * 256;

    const int lr = lane >> 2;
    const int lc = ((lane & 3) ^ ((lane >> 3) & 3)) * 8;   // swizzled source chunk
    const int rc = (lq ^ ((l16 >> 1) & 3)) * 8;            // swizzled read col

    // staging: A rows wave*64 + {0,16,32,48}; B rows wave*32 + {0,16}
    const f16* gA0 = A  + (size_t)(row0 + wave * 64 + lr) * E_ + lc;
    const f16* gB0 = Wo + (size_t)(col0 + wave * 32 + lr) * E_ + lc;
    const size_t rskip = (size_t)16 * E_;

    f32x4 zero4 = {0.f, 0.f, 0.f, 0.f};
    f32x4 acc[4][8];
    #pragma unroll
    for (int i = 0; i < 4; i++)
        #pragma unroll
        for (int j = 0; j < 8; j++) acc[i][j] = zero4;

    for (int kk = 0; kk < E_; kk += 64) {
        #pragma unroll
        for (int h = 0; h < 2; h++) {
            const int ko = kk + h * 32;
            #pragma unroll
            for (int j = 0; j < 4; j++)
                gload16(gA0 + (size_t)j * rskip + ko, &sA[h][wave * 64 + j * 16][0]);
            #pragma unroll
            for (int j = 0; j < 2; j++)
                gload16(gB0 + (size_t)j * rskip + ko, &sB[h][wave * 32 + j * 16][0]);
        }
        __syncthreads();

        #pragma unroll
        for (int h = 0; h < 2; h++) {
            f16x8 aF[4], bF[8];
            #pragma unroll
            for (int f = 0; f < 4; f++)
                aF[f] = *(const f16x8*)&sA[h][wave * 64 + f * 16 + l16][rc];
            #pragma unroll
            for (int g = 0; g < 8; g++)
                bF[g] = *(const f16x8*)&sB[h][g * 16 + l16][rc];
            #pragma unroll
            for (int fr = 0; fr < 4; fr++)
                #pragma unroll
                for (int fc = 0; fc < 8; fc++)
                    acc[fr][fc] = __builtin_amdgcn_mfma_f32_16x16x32_f16(aF[fr], bF[fc], acc[fr][fc], 0, 0, 0);
        }
        __syncthreads();
    }

    #pragma unroll
    for (int fc = 0; fc < 8; fc++) {
        int col = col0 + fc * 16 + l16;
        float bov = bo[col];
        #pragma unroll
        for (int fr = 0; fr < 4; fr++)
            #pragma unroll
            for (int e = 0; e < 4; e++) {
                int row = row0 + wave * 64 + fr * 16 + lq * 4 + e;
                a16[(size_t)row * E_ + col] = (f16)(acc[fr][fc][e] + bov);
            }
    }
}

// ---------------- resid-add + LayerNorm over E=1024 ----------------
// reads attn16 (f16) + image16 (f16 residual); writes normalized f32
__global__ __launch_bounds__(256) void ln_kernel(
    const f16* __restrict__ a16, const f16* __restrict__ resid16,
    const float* __restrict__ gamma, const float* __restrict__ beta,
    float* __restrict__ out)
{
    const int row = blockIdx.x;
    const int tid = threadIdx.x;
    union { ushort4 u; f16 h[4]; } ua, ur;
    ua.u = ((const ushort4*)(a16     + (size_t)row * E_))[tid];
    ur.u = ((const ushort4*)(resid16 + (size_t)row * E_))[tid];
    float4 v;
    v.x = (float)ua.h[0] + (float)ur.h[0];
    v.y = (float)ua.h[1] + (float)ur.h[1];
    v.z = (float)ua.h[2] + (float)ur.h[2];
    v.w = (float)ua.h[3] + (float)ur.h[3];
    float s  = v.x + v.y + v.z + v.w;
    float s2 = v.x * v.x + v.y * v.y + v.z * v.z + v.w * v.w;
    #pragma unroll
    for (int m = 1; m < 64; m <<= 1) {
        s  += __shfl_xor(s, m, 64);
        s2 += __shfl_xor(s2, m, 64);
    }
    __shared__ float red[8];
    int wv = tid >> 6, ln = tid & 63;
    if (ln == 0) { red[wv] = s; red[4 + wv] = s2; }
    __syncthreads();
    s  = red[0] + red[1] + red[2] + red[3];
    s2 = red[4] + red[5] + red[6] + red[7];
    float mu  = s * (1.0f / E_);
    float var = s2 * (1.0f / E_) - mu * mu;
    float r   = rsqrtf(var + 1e-5f);
    float4 g  = ((const float4*)gamma)[tid];
    float4 bb = ((const float4*)beta)[tid];
    float4 o;
    o.x = (v.x - mu) * r * g.x + bb.x;
    o.y = (v.y - mu) * r * g.y + bb.y;
    o.z = (v.z - mu) * r * g.z + bb.z;
    o.w = (v.w - mu) * r * g.w + bb.w;
    ((float4*)(out + (size_t)row * E_))[tid] = o;
}

extern "C" void kernel_launch(void* const* d_in, const int* in_sizes, int n_in,
                              void* d_out, int out_size, void* d_ws, size_t ws_size,
                              hipStream_t stream)
{
    (void)in_sizes; (void)n_in; (void)out_size; (void)ws_size;
    const float* image  = (const float*)d_in[0];
    const float* signal = (const float*)d_in[1];
    const float* Wq = (const float*)d_in[2];
    const float* Wk = (const float*)d_in[3];
    const float* Wv = (const float*)d_in[4];
    const float* bq = (const float*)d_in[5];
    const float* bk = (const float*)d_in[6];
    const float* bv = (const float*)d_in[7];
    const float* Wo = (const float*)d_in[8];
    const float* bo = (const float*)d_in[9];
    const float* gamma = (const float*)d_in[10];
    const float* beta  = (const float*)d_in[11];
    float* out = (float*)d_out;

    char* ws = (char*)d_ws;
    f16* Xi16 = (f16*)(ws);                            // 32 MB (image f16; resid for ln)
    f16* Xs16 = (f16*)(ws + 32ull * 1024 * 1024);      // 32 MB (reused as a16 after qkv)
    f16* Wq16 = (f16*)(ws + 64ull * 1024 * 1024);      // 2 MB
    f16* Wk16 = (f16*)(ws + 66ull * 1024 * 1024);      // 2 MB
    f16* Wv16 = (f16*)(ws + 68ull * 1024 * 1024);      // 2 MB
    f16* Wo16 = (f16*)(ws + 70ull * 1024 * 1024);      // 2 MB
    f16* ctx  = (f16*)(ws + 72ull * 1024 * 1024);      // 32 MB  (total 104 MB)
    f16* a16  = Xs16;                                  // Xs16 dead after qkv

    const int nBE4 = B_ * E_ / 4;   // 4194304
    const int nEE4 = E_ * E_ / 4;   // 262144
    dim3 gX(nBE4 / 256, 2);
    cvt2_kernel<<<gX, 256, 0, stream>>>((const float4*)image, (const float4*)signal,
                                        (ushort4*)Xi16, (ushort4*)Xs16, nBE4);
    dim3 gW(nEE4 / 256, 4);
    cvt4_kernel<<<gW, 256, 0, stream>>>((const float4*)Wq, (const float4*)Wk,
                                        (const float4*)Wv, (const float4*)Wo,
                                        (ushort4*)Wq16, (ushort4*)Wk16,
                                        (ushort4*)Wv16, (ushort4*)Wo16, nEE4);

    qkv_attn_kernel<<<B_ / 64 * H_, 256, 0, stream>>>(Xi16, Xs16, Wq16, Wk16, Wv16,
                                                      bq, bk, bv, ctx);

    out_proj_kernel<<<B_ / 256 * 8, 256, 0, stream>>>(ctx, Wo16, bo, a16);

    ln_kernel<<<B_, 256, 0, stream>>>(a16, Xi16, gamma, beta, out);
}

// Round 6
// 438.678 us; speedup vs baseline: 1.0863x; 1.0030x over previous
//
#include <hip/hip_runtime.h>

#define B_ 16384
#define E_ 1024
#define H_ 8
#define D_ 128

typedef _Float16 f16;
typedef _Float16 f16x8 __attribute__((ext_vector_type(8)));
typedef float f32x4 __attribute__((ext_vector_type(4)));

// async global -> LDS, 16B per lane. LDS dest is wave-uniform base + lane*16.
__device__ __forceinline__ void gload16(const f16* g, f16* l) {
    __builtin_amdgcn_global_load_lds(
        (const __attribute__((address_space(1))) void*)g,
        (__attribute__((address_space(3))) void*)l, 16, 0, 0);
}

// LDS XOR swizzle (within each 16-row x 32-col f16 tile staged by one gload16):
//   LDS chunk p (16B) of row r holds global chunk p ^ ((r>>1)&3).
// Write side: lane l (r=l>>2, p=l&3) sources global chunk (l&3)^((l>>3)&3).
// Read side: global chunk lq of row r lives at LDS chunk lq^((r>>1)&3).
// Verified round 2: SQ_LDS_BANK_CONFLICT 1.68e7 -> 0.
// Template law (r2-r5): 1-phase single-buffer BK=64 is the proven best schedule;
// occupancy (blocks/CU), not MFMA-per-barrier, is the out_proj lever under test.

// ---------------- f32 -> f16 conversion ----------------
__global__ __launch_bounds__(256) void cvt2_kernel(const float4* __restrict__ s0,
                                                   const float4* __restrict__ s1,
                                                   ushort4* __restrict__ d0,
                                                   ushort4* __restrict__ d1, int n4) {
    const float4* s = blockIdx.y ? s1 : s0;
    ushort4* d = blockIdx.y ? d1 : d0;
    int i = blockIdx.x * 256 + threadIdx.x;
    if (i >= n4) return;
    float4 v = s[i];
    union { ushort4 u; f16 h[4]; } o;
    o.h[0] = (f16)v.x; o.h[1] = (f16)v.y; o.h[2] = (f16)v.z; o.h[3] = (f16)v.w;
    d[i] = o.u;
}

__global__ __launch_bounds__(256) void cvt4_kernel(
    const float4* __restrict__ s0, const float4* __restrict__ s1,
    const float4* __restrict__ s2, const float4* __restrict__ s3,
    ushort4* __restrict__ d0, ushort4* __restrict__ d1,
    ushort4* __restrict__ d2, ushort4* __restrict__ d3, int n4) {
    const float4* s; ushort4* d;
    switch (blockIdx.y) {
        case 0: s = s0; d = d0; break;
        case 1: s = s1; d = d1; break;
        case 2: s = s2; d = d2; break;
        default: s = s3; d = d3; break;
    }
    int i = blockIdx.x * 256 + threadIdx.x;
    if (i >= n4) return;
    float4 v = s[i];
    union { ushort4 u; f16 h[4]; } o;
    o.h[0] = (f16)v.x; o.h[1] = (f16)v.y; o.h[2] = (f16)v.z; o.h[3] = (f16)v.w;
    d[i] = o.u;
}

// ---------------- fused single-pass QKV + 2-key attention -> ctx ----------------
// 1-D grid of 2048 blocks; head = bid & 7, rblk = bid >> 3.
// 256 threads = 4 waves, wave grid 2x2 over 64 rows x 128 cols. One K-pass computes
// Q, Kimg, Ksig, Vimg, Vsig; epilogue mixes ctx = a0*Vi + a1*Vs (softmax linearity).
// Single-buffer BK=64 (measured best: r2 195us BK32, r3 234us dbuf, r4 191us BK64).
__global__ __launch_bounds__(256, 2) void qkv_attn_kernel(
    const f16* __restrict__ Xi, const f16* __restrict__ Xs,
    const f16* __restrict__ Wq, const f16* __restrict__ Wk, const f16* __restrict__ Wv,
    const float* __restrict__ bq, const float* __restrict__ bk, const float* __restrict__ bv,
    f16* __restrict__ ctx)
{
    __shared__ f16 sAi[2][64][32];    // [half][row][col]  8 KB
    __shared__ f16 sAs[2][64][32];    //                   8 KB
    __shared__ f16 sWq[2][128][32];   //                  16 KB
    __shared__ f16 sWk[2][128][32];   //                  16 KB
    __shared__ f16 sWv[2][128][32];   //                  16 KB  (64 KB -> 2 blocks/CU)
    __shared__ float sdot[2][64][2];
    __shared__ float sa0[64];

    const int tid  = threadIdx.x;
    const int lane = tid & 63;
    const int wave = tid >> 6;
    const int wr = wave >> 1, wc = wave & 1;
    const int l16 = lane & 15, lq = lane >> 4;

    const int bid  = blockIdx.x;
    const int head = bid & 7;           // XCD-aligned head assignment
    const int row0 = (bid >> 3) * 64;
    const int col0 = head * D_;

    const int lr = lane >> 2;                                   // 0..15
    const int lc = ((lane & 3) ^ ((lane >> 3) & 3)) * 8;        // swizzled src chunk
    const int rc = (lq ^ ((l16 >> 1) & 3)) * 8;                 // swizzled read col

    const f16* gAi = Xi + (size_t)(row0 + wave * 16 + lr) * E_ + lc;
    const f16* gAs = Xs + (size_t)(row0 + wave * 16 + lr) * E_ + lc;
    const size_t woff = (size_t)(col0 + wave * 32 + lr) * E_ + lc;
    const f16* gWq = Wq + woff;
    const f16* gWk = Wk + woff;
    const f16* gWv = Wv + woff;
    const size_t wskip = (size_t)16 * E_;

    f32x4 zero4 = {0.f, 0.f, 0.f, 0.f};
    f32x4 accQ[2][4], accKi[2][4], accKs[2][4], accVi[2][4], accVs[2][4];
    #pragma unroll
    for (int i = 0; i < 2; i++)
        #pragma unroll
        for (int j = 0; j < 4; j++) {
            accQ[i][j] = zero4; accKi[i][j] = zero4; accKs[i][j] = zero4;
            accVi[i][j] = zero4; accVs[i][j] = zero4;
        }

    for (int kk = 0; kk < E_; kk += 64) {
        #pragma unroll
        for (int h = 0; h < 2; h++) {
            const int ko = kk + h * 32;
            gload16(gAi + ko,         &sAi[h][wave * 16][0]);
            gload16(gAs + ko,         &sAs[h][wave * 16][0]);
            gload16(gWq + ko,         &sWq[h][wave * 32][0]);
            gload16(gWq + wskip + ko, &sWq[h][wave * 32 + 16][0]);
            gload16(gWk + ko,         &sWk[h][wave * 32][0]);
            gload16(gWk + wskip + ko, &sWk[h][wave * 32 + 16][0]);
            gload16(gWv + ko,         &sWv[h][wave * 32][0]);
            gload16(gWv + wskip + ko, &sWv[h][wave * 32 + 16][0]);
        }
        __syncthreads();   // drains vmcnt -> tile resident

        #pragma unroll
        for (int h = 0; h < 2; h++) {
            f16x8 aI[2], aS[2], bF[4];
            #pragma unroll
            for (int fr = 0; fr < 2; fr++) {
                aI[fr] = *(const f16x8*)&sAi[h][wr * 32 + fr * 16 + l16][rc];
                aS[fr] = *(const f16x8*)&sAs[h][wr * 32 + fr * 16 + l16][rc];
            }
            #pragma unroll
            for (int fc = 0; fc < 4; fc++)
                bF[fc] = *(const f16x8*)&sWq[h][wc * 64 + fc * 16 + l16][rc];
            #pragma unroll
            for (int fr = 0; fr < 2; fr++)
                #pragma unroll
                for (int fc = 0; fc < 4; fc++)
                    accQ[fr][fc] = __builtin_amdgcn_mfma_f32_16x16x32_f16(aI[fr], bF[fc], accQ[fr][fc], 0, 0, 0);
            #pragma unroll
            for (int fc = 0; fc < 4; fc++)
                bF[fc] = *(const f16x8*)&sWk[h][wc * 64 + fc * 16 + l16][rc];
            #pragma unroll
            for (int fr = 0; fr < 2; fr++)
                #pragma unroll
                for (int fc = 0; fc < 4; fc++) {
                    accKi[fr][fc] = __builtin_amdgcn_mfma_f32_16x16x32_f16(aI[fr], bF[fc], accKi[fr][fc], 0, 0, 0);
                    accKs[fr][fc] = __builtin_amdgcn_mfma_f32_16x16x32_f16(aS[fr], bF[fc], accKs[fr][fc], 0, 0, 0);
                }
            #pragma unroll
            for (int fc = 0; fc < 4; fc++)
                bF[fc] = *(const f16x8*)&sWv[h][wc * 64 + fc * 16 + l16][rc];
            #pragma unroll
            for (int fr = 0; fr < 2; fr++)
                #pragma unroll
                for (int fc = 0; fc < 4; fc++) {
                    accVi[fr][fc] = __builtin_amdgcn_mfma_f32_16x16x32_f16(aI[fr], bF[fc], accVi[fr][fc], 0, 0, 0);
                    accVs[fr][fc] = __builtin_amdgcn_mfma_f32_16x16x32_f16(aS[fr], bF[fc], accVs[fr][fc], 0, 0, 0);
                }
        }
        __syncthreads();   // guard LDS reuse next iteration
    }

    #pragma unroll
    for (int fc = 0; fc < 4; fc++) {
        int col = col0 + wc * 64 + fc * 16 + l16;
        float bqv = bq[col], bkv = bk[col];
        #pragma unroll
        for (int fr = 0; fr < 2; fr++)
            #pragma unroll
            for (int e = 0; e < 4; e++) {
                accQ[fr][fc][e]  += bqv;
                accKi[fr][fc][e] += bkv;
                accKs[fr][fc][e] += bkv;
            }
    }

    // scores: per-row dot(q,k) over this head's 128 cols
    #pragma unroll
    for (int fr = 0; fr < 2; fr++)
        #pragma unroll
        for (int e = 0; e < 4; e++) {
            float d0 = 0.f, d1 = 0.f;
            #pragma unroll
            for (int fc = 0; fc < 4; fc++) {
                d0 += accQ[fr][fc][e] * accKi[fr][fc][e];
                d1 += accQ[fr][fc][e] * accKs[fr][fc][e];
            }
            #pragma unroll
            for (int m = 1; m < 16; m <<= 1) {
                d0 += __shfl_xor(d0, m, 64);
                d1 += __shfl_xor(d1, m, 64);
            }
            if (l16 == 0) {
                int row = wr * 32 + fr * 16 + lq * 4 + e;
                sdot[0][row][wc] = d0;
                sdot[1][row][wc] = d1;
            }
        }
    __syncthreads();
    if (tid < 64) {
        const float scale = 0.088388347648318447f;  // 1/sqrt(128)
        float s0 = (sdot[0][tid][0] + sdot[0][tid][1]) * scale;
        float s1 = (sdot[1][tid][0] + sdot[1][tid][1]) * scale;
        sa0[tid] = 1.0f / (1.0f + expf(s1 - s0));
    }
    __syncthreads();

    // ctx = a0*Vimg + a1*Vsig + bv, written f16
    #pragma unroll
    for (int fc = 0; fc < 4; fc++) {
        int col = col0 + wc * 64 + fc * 16 + l16;
        float bvv = bv[col];
        #pragma unroll
        for (int fr = 0; fr < 2; fr++)
            #pragma unroll
            for (int e = 0; e < 4; e++) {
                int row = wr * 32 + fr * 16 + lq * 4 + e;
                float a0 = sa0[row];
                float v  = a0 * accVi[fr][fc][e] + (1.0f - a0) * accVs[fr][fc][e] + bvv;
                ctx[(size_t)(row0 + row) * E_ + col] = (f16)v;
            }
    }
}

// ---------------- out projection: attn16 = ctx @ Wo^T + bo   (f16) ----------------
// 128x128 tile, acc[4][4]=64 VGPR, __launch_bounds__(256,4) pins <=128 VGPR ->
// 4 waves/SIMD -> 4 blocks/CU (32 KB LDS, 4x32=128 <= 160 OK). 1024 blocks,
// col-panel = bid&7 (per-XCD Wo L2 residence). Theory under test: all prior
// variants were VGPR-capped at 2 blocks/CU -> latency-exposed; 2x TLP fixes it.
__global__ __launch_bounds__(256, 4) void out_proj_kernel(
    const f16* __restrict__ A, const f16* __restrict__ Wo, const float* __restrict__ bo,
    f16* __restrict__ a16)
{
    __shared__ f16 sA[2][128][32];   // [half][row][col] 16 KB
    __shared__ f16 sB[2][128][32];   //                  16 KB
    const int tid  = threadIdx.x;
    const int lane = tid & 63;
    const int wave = tid >> 6;
    const int wr = wave >> 1, wc = wave & 1;
    const int l16 = lane & 15, lq = lane >> 4;

    const int bid  = blockIdx.x;
    const int col0 = (bid & 7) * 128;
    const int row0 = (bid >> 3) * 128;

    const int lr = lane >> 2;
    const int lc = ((lane & 3) ^ ((lane >> 3) & 3)) * 8;   // swizzled source chunk
    const int rc = (lq ^ ((l16 >> 1) & 3)) * 8;            // swizzled read col

    const f16* gA0 = A  + (size_t)(row0 + wave * 32 + lr) * E_ + lc;
    const f16* gB0 = Wo + (size_t)(col0 + wave * 32 + lr) * E_ + lc;
    const size_t wskip = (size_t)16 * E_;

    f32x4 zero4 = {0.f, 0.f, 0.f, 0.f};
    f32x4 acc[4][4];
    #pragma unroll
    for (int i = 0; i < 4; i++)
        #pragma unroll
        for (int j = 0; j < 4; j++) acc[i][j] = zero4;

    for (int kk = 0; kk < E_; kk += 64) {
        #pragma unroll
        for (int h = 0; h < 2; h++) {
            const int ko = kk + h * 32;
            gload16(gA0 + ko,         &sA[h][wave * 32][0]);
            gload16(gA0 + wskip + ko, &sA[h][wave * 32 + 16][0]);
            gload16(gB0 + ko,         &sB[h][wave * 32][0]);
            gload16(gB0 + wskip + ko, &sB[h][wave * 32 + 16][0]);
        }
        __syncthreads();

        #pragma unroll
        for (int h = 0; h < 2; h++) {
            f16x8 aF[4], bF[4];
            #pragma unroll
            for (int f = 0; f < 4; f++) {
                aF[f] = *(const f16x8*)&sA[h][wr * 64 + f * 16 + l16][rc];
                bF[f] = *(const f16x8*)&sB[h][wc * 64 + f * 16 + l16][rc];
            }
            #pragma unroll
            for (int fr = 0; fr < 4; fr++)
                #pragma unroll
                for (int fc = 0; fc < 4; fc++)
                    acc[fr][fc] = __builtin_amdgcn_mfma_f32_16x16x32_f16(aF[fr], bF[fc], acc[fr][fc], 0, 0, 0);
        }
        __syncthreads();
    }

    #pragma unroll
    for (int fc = 0; fc < 4; fc++) {
        int col = col0 + wc * 64 + fc * 16 + l16;
        float bov = bo[col];
        #pragma unroll
        for (int fr = 0; fr < 4; fr++)
            #pragma unroll
            for (int e = 0; e < 4; e++) {
                int row = row0 + wr * 64 + fr * 16 + lq * 4 + e;
                a16[(size_t)row * E_ + col] = (f16)(acc[fr][fc][e] + bov);
            }
    }
}

// ---------------- resid-add + LayerNorm over E=1024 ----------------
// reads attn16 (f16) + image16 (f16 residual); writes normalized f32
__global__ __launch_bounds__(256) void ln_kernel(
    const f16* __restrict__ a16, const f16* __restrict__ resid16,
    const float* __restrict__ gamma, const float* __restrict__ beta,
    float* __restrict__ out)
{
    const int row = blockIdx.x;
    const int tid = threadIdx.x;
    union { ushort4 u; f16 h[4]; } ua, ur;
    ua.u = ((const ushort4*)(a16     + (size_t)row * E_))[tid];
    ur.u = ((const ushort4*)(resid16 + (size_t)row * E_))[tid];
    float4 v;
    v.x = (float)ua.h[0] + (float)ur.h[0];
    v.y = (float)ua.h[1] + (float)ur.h[1];
    v.z = (float)ua.h[2] + (float)ur.h[2];
    v.w = (float)ua.h[3] + (float)ur.h[3];
    float s  = v.x + v.y + v.z + v.w;
    float s2 = v.x * v.x + v.y * v.y + v.z * v.z + v.w * v.w;
    #pragma unroll
    for (int m = 1; m < 64; m <<= 1) {
        s  += __shfl_xor(s, m, 64);
        s2 += __shfl_xor(s2, m, 64);
    }
    __shared__ float red[8];
    int wv = tid >> 6, ln = tid & 63;
    if (ln == 0) { red[wv] = s; red[4 + wv] = s2; }
    __syncthreads();
    s  = red[0] + red[1] + red[2] + red[3];
    s2 = red[4] + red[5] + red[6] + red[7];
    float mu  = s * (1.0f / E_);
    float var = s2 * (1.0f / E_) - mu * mu;
    float r   = rsqrtf(var + 1e-5f);
    float4 g  = ((const float4*)gamma)[tid];
    float4 bb = ((const float4*)beta)[tid];
    float4 o;
    o.x = (v.x - mu) * r * g.x + bb.x;
    o.y = (v.y - mu) * r * g.y + bb.y;
    o.z = (v.z - mu) * r * g.z + bb.z;
    o.w = (v.w - mu) * r * g.w + bb.w;
    ((float4*)(out + (size_t)row * E_))[tid] = o;
}

extern "C" void kernel_launch(void* const* d_in, const int* in_sizes, int n_in,
                              void* d_out, int out_size, void* d_ws, size_t ws_size,
                              hipStream_t stream)
{
    (void)in_sizes; (void)n_in; (void)out_size; (void)ws_size;
    const float* image  = (const float*)d_in[0];
    const float* signal = (const float*)d_in[1];
    const float* Wq = (const float*)d_in[2];
    const float* Wk = (const float*)d_in[3];
    const float* Wv = (const float*)d_in[4];
    const float* bq = (const float*)d_in[5];
    const float* bk = (const float*)d_in[6];
    const float* bv = (const float*)d_in[7];
    const float* Wo = (const float*)d_in[8];
    const float* bo = (const float*)d_in[9];
    const float* gamma = (const float*)d_in[10];
    const float* beta  = (const float*)d_in[11];
    float* out = (float*)d_out;

    char* ws = (char*)d_ws;
    f16* Xi16 = (f16*)(ws);                            // 32 MB (image f16; resid for ln)
    f16* Xs16 = (f16*)(ws + 32ull * 1024 * 1024);      // 32 MB (reused as a16 after qkv)
    f16* Wq16 = (f16*)(ws + 64ull * 1024 * 1024);      // 2 MB
    f16* Wk16 = (f16*)(ws + 66ull * 1024 * 1024);      // 2 MB
    f16* Wv16 = (f16*)(ws + 68ull * 1024 * 1024);      // 2 MB
    f16* Wo16 = (f16*)(ws + 70ull * 1024 * 1024);      // 2 MB
    f16* ctx  = (f16*)(ws + 72ull * 1024 * 1024);      // 32 MB  (total 104 MB)
    f16* a16  = Xs16;                                  // Xs16 dead after qkv

    const int nBE4 = B_ * E_ / 4;   // 4194304
    const int nEE4 = E_ * E_ / 4;   // 262144
    dim3 gX(nBE4 / 256, 2);
    cvt2_kernel<<<gX, 256, 0, stream>>>((const float4*)image, (const float4*)signal,
                                        (ushort4*)Xi16, (ushort4*)Xs16, nBE4);
    dim3 gW(nEE4 / 256, 4);
    cvt4_kernel<<<gW, 256, 0, stream>>>((const float4*)Wq, (const float4*)Wk,
                                        (const float4*)Wv, (const float4*)Wo,
                                        (ushort4*)Wq16, (ushort4*)Wk16,
                                        (ushort4*)Wv16, (ushort4*)Wo16, nEE4);

    qkv_attn_kernel<<<B_ / 64 * H_, 256, 0, stream>>>(Xi16, Xs16, Wq16, Wk16, Wv16,
                                                      bq, bk, bv, ctx);

    out_proj_kernel<<<B_ / 128 * 8, 256, 0, stream>>>(ctx, Wo16, bo, a16);

    ln_kernel<<<B_, 256, 0, stream>>>(a16, Xi16, gamma, beta, out);
}